// Round 10
// baseline (270.944 us; speedup 1.0000x reference)
//
#include <hip/hip_runtime.h>
#include <math.h>

#define F_IN  512
#define F_HID 256
#define F_OUT 64

typedef __attribute__((ext_vector_type(8))) short bf16x8;
typedef __attribute__((ext_vector_type(4))) short bf16x4;
typedef __attribute__((ext_vector_type(4))) float f32x4;

#define GLOBAL_AS __attribute__((address_space(1)))
#define LDS_AS    __attribute__((address_space(3)))

__device__ __forceinline__ void gload_lds16(const ushort* g, ushort* l) {
    __builtin_amdgcn_global_load_lds((const GLOBAL_AS uint32_t*)g,
                                     (LDS_AS uint32_t*)l, 16, 0, 0);
}

__device__ __forceinline__ ushort f2bf(float f) {
    union { float f; uint32_t u; } v; v.f = f;
    uint32_t r = (v.u + 0x7FFFu + ((v.u >> 16) & 1u)) >> 16;
    return (ushort)r;
}

__device__ __forceinline__ float bf2f(ushort u) {
    union { uint32_t u; float f; } v; v.u = ((uint32_t)u) << 16;
    return v.f;
}

__device__ __forceinline__ bf16x8 conv8(float4 a, float4 b) {
    bf16x8 c;
    c[0] = (short)f2bf(a.x); c[1] = (short)f2bf(a.y);
    c[2] = (short)f2bf(a.z); c[3] = (short)f2bf(a.w);
    c[4] = (short)f2bf(b.x); c[5] = (short)f2bf(b.y);
    c[6] = (short)f2bf(b.z); c[7] = (short)f2bf(b.w);
    return c;
}

// ---------------- degree ----------------
__global__ void k_deg(const int* __restrict__ dst, int* __restrict__ deg, int E) {
    int e = blockIdx.x * 256 + threadIdx.x;
    if (e < E) atomicAdd(&deg[dst[e]], 1);
}

// ---------------- scan level 1 (+ dinv fused) ----------------
__global__ void k_scan1(const int* __restrict__ deg, int* __restrict__ offs,
                        int* __restrict__ bsums, float* __restrict__ dinv, int N) {
    __shared__ int s[256];
    int tid = threadIdx.x;
    int i = blockIdx.x * 256 + tid;
    int v = (i < N) ? deg[i] : 0;
    if (i < N) dinv[i] = rsqrtf((float)(v + 1));   // +1 self loop
    s[tid] = v; __syncthreads();
    for (int d = 1; d < 256; d <<= 1) {
        int t = (tid >= d) ? s[tid - d] : 0;
        __syncthreads();
        s[tid] += t;
        __syncthreads();
    }
    if (i < N) offs[i] = s[tid] - v;
    if (tid == 255) bsums[blockIdx.x] = s[255];
}

__global__ void k_scan2(int* __restrict__ bsums, int n) {
    __shared__ int s[256];
    int tid = threadIdx.x;
    int v = (tid < n) ? bsums[tid] : 0;
    s[tid] = v; __syncthreads();
    for (int d = 1; d < 256; d <<= 1) {
        int t = (tid >= d) ? s[tid - d] : 0;
        __syncthreads();
        s[tid] += t;
        __syncthreads();
    }
    if (tid < n) bsums[tid] = s[tid] - v;
}

__global__ void k_scan3(int* __restrict__ offs, const int* __restrict__ bsums,
                        int* __restrict__ cursor, int2* __restrict__ jw, int N, int E) {
    int i = blockIdx.x * 256 + threadIdx.x;
    if (i < N) {
        int o = offs[i] + bsums[i >> 8];
        offs[i] = o;
        cursor[i] = o;
    }
    if (i == 0) offs[N] = E;
    if (i < 16) jw[E + i] = make_int2(0, 0);   // pad: row 0, weight 0
}

// fill packed (src_index, dinv[src]) per CSR slot
__global__ void k_fill(const int* __restrict__ src, const int* __restrict__ dst,
                       int* __restrict__ cursor, int2* __restrict__ jw,
                       const float* __restrict__ dinv, int E) {
    int e = blockIdx.x * 256 + threadIdx.x;
    if (e < E) {
        int s = src[e];
        int pos = atomicAdd(&cursor[dst[e]], 1);
        jw[pos] = make_int2(s, __float_as_int(dinv[s]));
    }
}

// ---------------- weight transpose-casts (W1 and W2 in one launch) ----------------
__global__ void k_tcast2(const float* __restrict__ W1, ushort* __restrict__ w1t,
                         const float* __restrict__ W2, ushort* __restrict__ w2t) {
    int idx = blockIdx.x * 256 + threadIdx.x;
    const int n1 = F_IN * F_HID;
    if (idx < n1) {
        int n = idx / F_IN, k = idx - n * F_IN;
        w1t[idx] = f2bf(W1[(size_t)k * F_HID + n]);
    } else {
        int t = idx - n1;
        if (t < F_HID * F_OUT) {
            int n = t / F_HID, k = t - n * F_HID;
            w2t[t] = f2bf(W2[(size_t)k * F_OUT + n]);
        }
    }
}

// ---------------- GEMM1: h1[M,256] = bf16( fp32 x[M,512] @ w1t^T ) ----------------
// BM=64 x BN=64 -> 3128 blocks (~12/CU queued, 9/CU LDS cap). 4 waves 2x2, each
// 32x32 (acc 16 VGPR). Double-buffered; A pipeline: load(t+2)/convert(t+1)/compute(t).
// B via gload_lds with chunk-XOR swizzle. x re-reads across 4 col-blocks are L3-served.
__global__ __launch_bounds__(256) void k_gemm1(
        const float* __restrict__ A, const ushort* __restrict__ Bt,
        ushort* __restrict__ C, int M) {
    constexpr int K = F_IN, Nc = F_HID, BM = 64, BN = 64, NT = K / 32;
    constexpr int ASTR = 36;
    __shared__ ushort As[2][BM * ASTR];
    __shared__ ushort Bs[2][BN * 32];
    const int tid  = threadIdx.x;
    const int wave = tid >> 6, lane = tid & 63;
    const int wr = wave & 1, wc = wave >> 1;
    const int brow = blockIdx.y * BM, bcol = blockIdx.x * BN;

    f32x4 acc[2][2];
    #pragma unroll
    for (int m = 0; m < 2; ++m)
        #pragma unroll
        for (int n = 0; n < 2; ++n) acc[m][n] = (f32x4){0.f, 0.f, 0.f, 0.f};

    // A stage: 4 thr/row, 8 fp32 (2 float4) each
    const int arow = tid >> 2;
    const int akc  = (tid & 3) * 8;
    int agrow = brow + arow; if (agrow >= M) agrow = M - 1;
    const float4* ap = (const float4*)&A[(size_t)agrow * K + akc];   // iter t: ap[t*8+q]
    // B stage: 4 thr/row, chunk-XOR pre-swizzled source (same 64B line)
    const int csrc = (tid & 3) ^ ((tid >> 3) & 3);
    const ushort* bp = &Bt[(size_t)(bcol + (tid >> 2)) * K + csrc * 8];

    const int kqA = (lane >> 4) * 8;
    const int kqB = ((lane >> 4) ^ ((lane >> 1) & 3)) * 8;   // undo store swizzle
    const int rA0 = wr * 32 + (lane & 15);
    const int rB0 = wc * 32 + (lane & 15);

    float4 rg[2][2];

    // ---- prologue: A(0)->conv->As[0]; B(0)->Bs[0]; A(1)->regs ----
    rg[0][0] = ap[0]; rg[0][1] = ap[1];
    gload_lds16(bp, &Bs[0][wave * 512]);
    *(bf16x8*)&As[0][arow * ASTR + akc] = conv8(rg[0][0], rg[0][1]);
    rg[1][0] = ap[8]; rg[1][1] = ap[9];
    __syncthreads();

    #pragma unroll
    for (int t = 0; t < NT; ++t) {
        const int b = t & 1;
        if (t + 1 < NT) {
            gload_lds16(bp + (t + 1) * 32, &Bs[b ^ 1][wave * 512]);
            // convert A(t+1) (regs issued one iteration ago)
            *(bf16x8*)&As[b ^ 1][arow * ASTR + akc] =
                conv8(rg[(t + 1) & 1][0], rg[(t + 1) & 1][1]);
        }
        if (t + 2 < NT) {
            // issue A(t+2) into the set just consumed (full-iter latency distance)
            rg[t & 1][0] = ap[(t + 2) * 8];
            rg[t & 1][1] = ap[(t + 2) * 8 + 1];
        }
        bf16x8 af[2], bfr[2];
        #pragma unroll
        for (int m = 0; m < 2; ++m)
            af[m] = *(const bf16x8*)&As[b][(rA0 + m * 16) * ASTR + kqA];
        #pragma unroll
        for (int n = 0; n < 2; ++n)
            bfr[n] = *(const bf16x8*)&Bs[b][(rB0 + n * 16) * 32 + kqB];
        #pragma unroll
        for (int m = 0; m < 2; ++m)
            #pragma unroll
            for (int n = 0; n < 2; ++n)
                acc[m][n] = __builtin_amdgcn_mfma_f32_16x16x32_bf16(af[m], bfr[n], acc[m][n], 0, 0, 0);
        if (t + 1 < NT) __syncthreads();
    }

    const int crow0 = brow + wr * 32 + (lane >> 4) * 4;
    const int ccol0 = bcol + wc * 32 + (lane & 15);
    #pragma unroll
    for (int m = 0; m < 2; ++m)
        #pragma unroll
        for (int n = 0; n < 2; ++n)
            #pragma unroll
            for (int j = 0; j < 4; ++j) {
                int row = crow0 + m * 16 + j;
                if (row < M) C[(size_t)row * Nc + ccol0 + n * 16] = f2bf(acc[m][n][j]);
            }
}

// ---------------- bf16 MFMA GEMM2: C[M,Nc] = A[M,K] @ Bt[Nc,K]^T (bf16 out) ----------------
template<int WR, int WC, int MR, int NR>
__global__ __launch_bounds__(256) void k_gemm_bf16(
        const ushort* __restrict__ A, const ushort* __restrict__ Bt,
        ushort* __restrict__ C, int M, int K, int Nc) {
    constexpr int BM = WR * MR * 16;
    constexpr int BN = WC * NR * 16;
    __shared__ ushort As[BM * 32];
    __shared__ ushort Bs[BN * 32];
    const int tid  = threadIdx.x;
    const int wave = tid >> 6, lane = tid & 63;
    const int wr = wave % WR, wc = wave / WR;
    const int brow = blockIdx.y * BM, bcol = blockIdx.x * BN;

    f32x4 acc[MR][NR];
    #pragma unroll
    for (int m = 0; m < MR; ++m)
        #pragma unroll
        for (int n = 0; n < NR; ++n) acc[m][n] = (f32x4){0.f, 0.f, 0.f, 0.f};

    const int srow = tid >> 2;
    const int scol = (tid & 3) * 8;
    const int kq  = (lane >> 4) * 8;
    const int rA0 = wr * MR * 16 + (lane & 15);
    const int rB0 = wc * NR * 16 + (lane & 15);

    for (int k0 = 0; k0 < K; k0 += 32) {
        #pragma unroll
        for (int l = 0; l < BM / 64; ++l) {
            int row = brow + l * 64 + srow;
            if (row >= M) row = M - 1;
            gload_lds16(&A[(size_t)row * K + k0 + scol], &As[l * 2048 + wave * 512]);
        }
        #pragma unroll
        for (int l = 0; l < BN / 64; ++l) {
            int row = bcol + l * 64 + srow;
            gload_lds16(&Bt[(size_t)row * K + k0 + scol], &Bs[l * 2048 + wave * 512]);
        }
        __syncthreads();
        bf16x8 af[MR], bfr[NR];
        #pragma unroll
        for (int m = 0; m < MR; ++m)
            af[m] = *(const bf16x8*)&As[(rA0 + m * 16) * 32 + kq];
        #pragma unroll
        for (int n = 0; n < NR; ++n)
            bfr[n] = *(const bf16x8*)&Bs[(rB0 + n * 16) * 32 + kq];
        #pragma unroll
        for (int m = 0; m < MR; ++m)
            #pragma unroll
            for (int n = 0; n < NR; ++n)
                acc[m][n] = __builtin_amdgcn_mfma_f32_16x16x32_bf16(af[m], bfr[n], acc[m][n], 0, 0, 0);
        __syncthreads();
    }

    const int crow0 = brow + wr * MR * 16 + (lane >> 4) * 4;
    const int ccol0 = bcol + wc * NR * 16 + (lane & 15);
    #pragma unroll
    for (int m = 0; m < MR; ++m)
        #pragma unroll
        for (int n = 0; n < NR; ++n)
            #pragma unroll
            for (int j = 0; j < 4; ++j) {
                int row = crow0 + m * 16 + j;
                if (row < M) C[(size_t)row * Nc + ccol0 + n * 16] = f2bf(acc[m][n][j]);
            }
}

// ---------------- layer-1 aggregation: paired-row gathers ----------------
__global__ __launch_bounds__(256) void k_agg1(
        const ushort* __restrict__ h, const int2* __restrict__ jw,
        const int* __restrict__ offs, const float* __restrict__ dinv,
        const float* __restrict__ bias, ushort* __restrict__ outm, int N) {
    int wave = threadIdx.x >> 6, lane = threadIdx.x & 63;
    int i = blockIdx.x * 4 + wave;
    if (i >= N) return;
    int g = lane & 31;        // features g*8 .. g*8+7
    int p = lane >> 5;        // edge parity
    float di = dinv[i];
    float acc[8];
    {
        bf16x8 hv = *(const bf16x8*)&h[(size_t)i * F_HID + g * 8];
        float w = (p == 0) ? di * di : 0.f;     // self loop counted once
        #pragma unroll
        for (int k = 0; k < 8; ++k) acc[k] = bf2f((ushort)hv[k]) * w;
    }
    int s = offs[i], e = offs[i + 1];
    for (int u = s; u < e; u += 12) {
        int2 a[6];
        #pragma unroll
        for (int q = 0; q < 6; ++q) a[q] = jw[u + 2 * q + p];   // overrun -> pad/next-node, masked
        bf16x8 hv[6];
        #pragma unroll
        for (int q = 0; q < 6; ++q)
            hv[q] = *(const bf16x8*)&h[(size_t)a[q].x * F_HID + g * 8];
        #pragma unroll
        for (int q = 0; q < 6; ++q) {
            float ww = (u + 2 * q + p < e) ? __int_as_float(a[q].y) * di : 0.f;
            #pragma unroll
            for (int k = 0; k < 8; ++k) acc[k] += bf2f((ushort)hv[q][k]) * ww;
        }
    }
    #pragma unroll
    for (int k = 0; k < 8; ++k) acc[k] += __shfl_xor(acc[k], 32, 64);
    if (p == 0) {
        float4 b0 = *(const float4*)&bias[g * 8];
        float4 b1 = *(const float4*)&bias[g * 8 + 4];
        bf16x8 o;
        o[0] = (short)f2bf(fmaxf(acc[0] + b0.x, 0.f));
        o[1] = (short)f2bf(fmaxf(acc[1] + b0.y, 0.f));
        o[2] = (short)f2bf(fmaxf(acc[2] + b0.z, 0.f));
        o[3] = (short)f2bf(fmaxf(acc[3] + b0.w, 0.f));
        o[4] = (short)f2bf(fmaxf(acc[4] + b1.x, 0.f));
        o[5] = (short)f2bf(fmaxf(acc[5] + b1.y, 0.f));
        o[6] = (short)f2bf(fmaxf(acc[6] + b1.z, 0.f));
        o[7] = (short)f2bf(fmaxf(acc[7] + b1.w, 0.f));
        *(bf16x8*)&outm[(size_t)i * F_HID + g * 8] = o;
    }
}

// ---------------- layer-2 aggregation + bias + log_softmax: wave per node, 8-unroll ----------------
__global__ __launch_bounds__(256) void k_agg2(
        const ushort* __restrict__ h, const int2* __restrict__ jw,
        const int* __restrict__ offs, const float* __restrict__ dinv,
        const float* __restrict__ bias, float* __restrict__ outm, int N) {
    int wave = threadIdx.x >> 6, lane = threadIdx.x & 63;
    int i = blockIdx.x * 4 + wave;
    if (i >= N) return;
    float di = dinv[i];
    float acc = bf2f(h[(size_t)i * F_OUT + lane]) * di * di;
    int s = offs[i], e = offs[i + 1];
    for (int u = s; u < e; u += 8) {
        int2 a[8];
        #pragma unroll
        for (int q = 0; q < 8; ++q) a[q] = jw[u + q];
        float hv[8];
        #pragma unroll
        for (int q = 0; q < 8; ++q)
            hv[q] = bf2f(h[(size_t)a[q].x * F_OUT + lane]);
        #pragma unroll
        for (int q = 0; q < 8; ++q) {
            float ww = (u + q < e) ? __int_as_float(a[q].y) * di : 0.f;
            acc += hv[q] * ww;
        }
    }
    acc += bias[lane];
    float m = acc;
    #pragma unroll
    for (int o = 32; o >= 1; o >>= 1) m = fmaxf(m, __shfl_xor(m, o, 64));
    float ex = expf(acc - m);
    float ssum = ex;
    #pragma unroll
    for (int o = 32; o >= 1; o >>= 1) ssum += __shfl_xor(ssum, o, 64);
    outm[(size_t)i * F_OUT + lane] = acc - m - logf(ssum);
}

extern "C" void kernel_launch(void* const* d_in, const int* in_sizes, int n_in,
                              void* d_out, int out_size, void* d_ws, size_t ws_size,
                              hipStream_t stream) {
    const float* x  = (const float*)d_in[0];
    const int*   ei = (const int*)d_in[1];
    const float* W1 = (const float*)d_in[2];
    const float* b1 = (const float*)d_in[3];
    const float* W2 = (const float*)d_in[4];
    const float* b2 = (const float*)d_in[5];
    float* out = (float*)d_out;

    int N = in_sizes[0] / F_IN;   // 50000
    int E = in_sizes[1] / 2;      // 800000
    const int* src = ei;
    const int* dst = ei + E;

    // workspace layout (16B aligned by construction)
    ushort* w1t = (ushort*)d_ws;                        // 256*512
    ushort* w2t = w1t + F_HID * F_IN;                   // 64*256
    ushort* h1  = w2t + F_OUT * F_HID;                  // N*256 bf16
    ushort* a1  = h1 + (size_t)N * F_HID;               // N*256 bf16
    int*    deg = (int*)(a1 + (size_t)N * F_HID);       // N
    float*  dinv = (float*)(deg + N);                   // N
    int*    offs = (int*)(dinv + N);                    // N+1
    int*    cursor = offs + N + 1;                      // N
    int*    bsums  = cursor + N;                        // 256
    int2*   jw = (int2*)(((uintptr_t)(bsums + 256) + 7) & ~(uintptr_t)7);  // E+16
    ushort* h2 = h1;     // alias: h1 dead after agg1

    int nch = (N + 255) / 256;

    hipMemsetAsync(deg, 0, sizeof(int) * N, stream);
    k_deg <<<(E + 255) / 256, 256, 0, stream>>>(dst, deg, E);
    k_scan1<<<nch, 256, 0, stream>>>(deg, offs, bsums, dinv, N);
    k_scan2<<<1, 256, 0, stream>>>(bsums, nch);
    k_scan3<<<nch, 256, 0, stream>>>(offs, bsums, cursor, jw, N, E);
    k_fill<<<(E + 255) / 256, 256, 0, stream>>>(src, dst, cursor, jw, dinv, E);

    // weight transpose-casts (one launch)
    int ntc = F_IN * F_HID + F_HID * F_OUT;
    k_tcast2<<<(ntc + 255) / 256, 256, 0, stream>>>(W1, w1t, W2, w2t);

    // layer 1: fused cast+GEMM (64x64 tile, 3128 blocks) + paired-gather aggregate
    k_gemm1<<<dim3(F_HID / 64, (N + 63) / 64), 256, 0, stream>>>(x, w1t, h1, N);
    k_agg1<<<(N + 3) / 4, 256, 0, stream>>>(h1, jw, offs, dinv, b1, a1, N);

    // layer 2: GEMM (64x64 tile, 782 blocks) + aggregate + log_softmax
    k_gemm_bf16<4, 1, 1, 4><<<dim3(1, (N + 63) / 64), 256, 0, stream>>>(
        a1, w2t, h2, N, F_HID, F_OUT);
    k_agg2<<<(N + 3) / 4, 256, 0, stream>>>(h2, jw, offs, dinv, b2, out, N);
}